// Round 9
// baseline (278.566 us; speedup 1.0000x reference)
//
#include <hip/hip_runtime.h>

typedef __attribute__((ext_vector_type(8))) __bf16 bf16x8;
typedef __attribute__((ext_vector_type(4))) __bf16 bf16x4;
typedef __attribute__((ext_vector_type(4))) float f32x4;
typedef __attribute__((ext_vector_type(16))) float f32x16;

#define GLDS(g, l) __builtin_amdgcn_global_load_lds( \
    (__attribute__((address_space(1))) void*)(void*)(g), \
    (__attribute__((address_space(3))) void*)(void*)(l), 16, 0, 0)

constexpr int T_REAL = 2049;   // sequence length
constexpr int Tp     = 2112;   // padded to 33*64
constexpr int Mreal  = 8196;   // 4*2049
constexpr int Mp     = 8448;   // padded to 33*256 (256-tile GEMM)
constexpr int GK     = 1024;   // C

// q pre-scale: 1/sqrt(64) * log2(e)  -> softmax runs in exp2 domain
constexpr float QSCALE = 0.125f * 1.4426950408889634f;

// ---------------- fused prep: cvt_x + transpose_w(Wa) + transpose_w(Wp) -------
__global__ __launch_bounds__(256)
void prep(const float* __restrict__ x, __bf16* __restrict__ xb,
          const float* __restrict__ Wa, __bf16* __restrict__ WaT,
          const float* __restrict__ Wp, __bf16* __restrict__ WpT) {
    __shared__ float tile[64][65];
    const int z = blockIdx.x;
    if (z < 8448) {               // ---- cvt_x: fp32 -> bf16, zero-pad rows ----
        size_t i = ((size_t)z * 256 + threadIdx.x) * 4;
        float4 v = make_float4(0.f, 0.f, 0.f, 0.f);
        if (i < (size_t)Mreal * GK) v = *(const float4*)(x + i);
        bf16x4 o;
        o.x = (__bf16)v.x; o.y = (__bf16)v.y; o.z = (__bf16)v.z; o.w = (__bf16)v.w;
        *(bf16x4*)(xb + i) = o;
        return;
    }
    const float* W; __bf16* Wt; int N, idx;
    if (z < 9216) { W = Wa; Wt = WaT; N = 3072; idx = z - 8448; }
    else          { W = Wp; Wt = WpT; N = 1024; idx = z - 9216; }
    const int ntiles = N >> 6;
    const int n0 = (idx % ntiles) * 64, k0 = (idx / ntiles) * 64;
    const int tx = threadIdx.x & 63, ty = threadIdx.x >> 6;
#pragma unroll
    for (int j = 0; j < 16; j++) {
        int rk = ty + j * 4;
        tile[rk][tx] = W[(size_t)(k0 + rk) * N + n0 + tx];
    }
    __syncthreads();
#pragma unroll
    for (int j = 0; j < 16; j++) {
        int rn = ty + j * 4;
        Wt[(size_t)(n0 + rn) * GK + k0 + tx] = (__bf16)tile[tx][rn];
    }
}

// ---------------- transpose v: [bh][t][d] -> [bh][d][t] ----------------
__global__ __launch_bounds__(256) void transpose_v(const __bf16* __restrict__ v,
                                                   __bf16* __restrict__ vT) {
    __shared__ __bf16 tl[64][72];   // stride 72 els = 144B rows, 16B-aligned
    const int bh = blockIdx.y, t0 = blockIdx.x * 64;
    const int tid = threadIdx.x;
    const __bf16* src = v + ((size_t)bh * Tp + t0) * 64;
    {
        const int r = tid >> 3, c = (tid & 7) * 8;
        *(bf16x8*)&tl[r][c]      = *(const bf16x8*)(src + r * 64 + c);
        *(bf16x8*)&tl[r + 32][c] = *(const bf16x8*)(src + (r + 32) * 64 + c);
    }
    __syncthreads();
    __bf16* dst = vT + (size_t)bh * 64 * Tp + t0;
    {
        const int d = tid >> 3, tc = (tid & 7) * 8;
        bf16x8 a, b;
#pragma unroll
        for (int i = 0; i < 8; i++) {
            a[i] = tl[tc + i][d];
            b[i] = tl[tc + i][d + 32];
        }
        *(bf16x8*)(dst + (size_t)d * Tp + tc)        = a;
        *(bf16x8*)(dst + (size_t)(d + 32) * Tp + tc) = b;
    }
}

// ---------------- 256x256x64 8-phase pipelined QKV GEMM ----------------
// This round: epilogue uses 4 scratch regions (2 in As flat, 2 in Bs flat),
// 4 frags per barrier pair -> 4 barriers total instead of 16.
__global__ __launch_bounds__(512)
void gemm256(const __bf16* __restrict__ A, const __bf16* __restrict__ Bt,
             __bf16* __restrict__ qout, __bf16* __restrict__ kout,
             __bf16* __restrict__ vout) {
    __shared__ __align__(16) __bf16 As[2][16384];   // 2 x 32 KB
    __shared__ __align__(16) __bf16 Bs[2][16384];   // 2 x 32 KB

    const int tid = threadIdx.x, lane = tid & 63, w = tid >> 6;
    const int wr = w >> 2, wc = w & 3;
    const int quad = lane >> 4, l15 = lane & 15, l7 = l15 & 7;
    const int m0 = blockIdx.y * 256, n0 = blockIdx.x * 256;

    const int sr = tid >> 3;                       // 0..63
    const int sc = ((tid & 7) ^ (sr & 7)) * 8;
    const __bf16* ag = A  + (size_t)(m0 + sr) * GK + sc;
    const __bf16* bg = Bt + (size_t)(n0 + sr) * GK + sc;
    const int ldst = tid * 8;

#define STG_A(T, h) do { const __bf16* s_ = ag + (size_t)(h) * 128 * GK + (T) * 64; \
    GLDS(s_, &As[(T) & 1][(h) * 8192 + ldst]); \
    GLDS(s_ + (size_t)64 * GK, &As[(T) & 1][(h) * 8192 + 4096 + ldst]); } while (0)
#define STG_B(T, h) do { const __bf16* s_ = bg + (size_t)(h) * 128 * GK + (T) * 64; \
    GLDS(s_, &Bs[(T) & 1][(h) * 8192 + ldst]); \
    GLDS(s_ + (size_t)64 * GK, &Bs[(T) & 1][(h) * 8192 + 4096 + ldst]); } while (0)

    f32x4 acc[8][4] = {};
    bf16x8 a[8], b0[4], b1[4];

    STG_A(0, 0); STG_B(0, 1); STG_A(0, 1); STG_B(0, 0); STG_A(1, 0); STG_B(1, 1);
    asm volatile("s_waitcnt vmcnt(4)" ::: "memory");
    __builtin_amdgcn_s_barrier();

    constexpr int NT = GK / 64;   // 16

#pragma unroll 1
    for (int T = 0; T < NT; ++T) {
        const int p = T & 1;

        // ---------- phase 1: read A0 + B0; stage A1/B0(T+1) ----------
#pragma unroll
        for (int f = 0; f < 4; ++f) {
            const int R = f * 32 + wr * 16 + l15;
            a[f * 2 + 0] = *(const bf16x8*)&As[p][R * 64 + ((quad ^ l7) * 8)];
            a[f * 2 + 1] = *(const bf16x8*)&As[p][R * 64 + (((4 + quad) ^ l7) * 8)];
        }
#pragma unroll
        for (int n = 0; n < 2; ++n) {
            const int R = n * 64 + wc * 16 + l15;
            b0[n * 2 + 0] = *(const bf16x8*)&Bs[p][R * 64 + ((quad ^ l7) * 8)];
            b0[n * 2 + 1] = *(const bf16x8*)&Bs[p][R * 64 + (((4 + quad) ^ l7) * 8)];
        }
        if (T + 1 < NT) { STG_A(T + 1, 1); STG_B(T + 1, 0); }
        __builtin_amdgcn_s_barrier();
        asm volatile("s_waitcnt lgkmcnt(0)" ::: "memory");
        __builtin_amdgcn_sched_barrier(0);
        __builtin_amdgcn_s_setprio(1);
#pragma unroll
        for (int f = 0; f < 4; ++f)
#pragma unroll
            for (int n = 0; n < 2; ++n) {
                acc[f][n] = __builtin_amdgcn_mfma_f32_16x16x32_bf16(a[f*2+0], b0[n*2+0], acc[f][n], 0, 0, 0);
                acc[f][n] = __builtin_amdgcn_mfma_f32_16x16x32_bf16(a[f*2+1], b0[n*2+1], acc[f][n], 0, 0, 0);
            }
        __builtin_amdgcn_s_setprio(0);
        __builtin_amdgcn_s_barrier();

        // ---------- phase 2: read B1; MFMA m0-3 x n2-3 ----------
#pragma unroll
        for (int n = 0; n < 2; ++n) {
            const int R = 128 + n * 64 + wc * 16 + l15;
            b1[n * 2 + 0] = *(const bf16x8*)&Bs[p][R * 64 + ((quad ^ l7) * 8)];
            b1[n * 2 + 1] = *(const bf16x8*)&Bs[p][R * 64 + (((4 + quad) ^ l7) * 8)];
        }
        __builtin_amdgcn_s_barrier();
        asm volatile("s_waitcnt lgkmcnt(0)" ::: "memory");
        __builtin_amdgcn_sched_barrier(0);
        __builtin_amdgcn_s_setprio(1);
#pragma unroll
        for (int f = 0; f < 4; ++f)
#pragma unroll
            for (int n = 0; n < 2; ++n) {
                acc[f][2+n] = __builtin_amdgcn_mfma_f32_16x16x32_bf16(a[f*2+0], b1[n*2+0], acc[f][2+n], 0, 0, 0);
                acc[f][2+n] = __builtin_amdgcn_mfma_f32_16x16x32_bf16(a[f*2+1], b1[n*2+1], acc[f][2+n], 0, 0, 0);
            }
        __builtin_amdgcn_s_setprio(0);
        __builtin_amdgcn_s_barrier();

        // ---------- phase 3: read A1; stage A0(T+2); MFMA m4-7 x n2-3 ----------
#pragma unroll
        for (int f = 0; f < 4; ++f) {
            const int R = 128 + f * 32 + wr * 16 + l15;
            a[f * 2 + 0] = *(const bf16x8*)&As[p][R * 64 + ((quad ^ l7) * 8)];
            a[f * 2 + 1] = *(const bf16x8*)&As[p][R * 64 + (((4 + quad) ^ l7) * 8)];
        }
        if (T + 2 < NT) STG_A(T + 2, 0);
        __builtin_amdgcn_s_barrier();
        asm volatile("s_waitcnt lgkmcnt(0)" ::: "memory");
        __builtin_amdgcn_sched_barrier(0);
        __builtin_amdgcn_s_setprio(1);
#pragma unroll
        for (int f = 0; f < 4; ++f)
#pragma unroll
            for (int n = 0; n < 2; ++n) {
                acc[4+f][2+n] = __builtin_amdgcn_mfma_f32_16x16x32_bf16(a[f*2+0], b1[n*2+0], acc[4+f][2+n], 0, 0, 0);
                acc[4+f][2+n] = __builtin_amdgcn_mfma_f32_16x16x32_bf16(a[f*2+1], b1[n*2+1], acc[4+f][2+n], 0, 0, 0);
            }
        __builtin_amdgcn_s_setprio(0);
        __builtin_amdgcn_s_barrier();

        // ---------- phase 4: stage B1(T+2); MFMA m4-7 x n0-1; counted vmcnt ----------
        if (T + 2 < NT) STG_B(T + 2, 1);
        __builtin_amdgcn_s_barrier();
        asm volatile("s_waitcnt lgkmcnt(0)" ::: "memory");
        __builtin_amdgcn_sched_barrier(0);
        __builtin_amdgcn_s_setprio(1);
#pragma unroll
        for (int f = 0; f < 4; ++f)
#pragma unroll
            for (int n = 0; n < 2; ++n) {
                acc[4+f][n] = __builtin_amdgcn_mfma_f32_16x16x32_bf16(a[f*2+0], b0[n*2+0], acc[4+f][n], 0, 0, 0);
                acc[4+f][n] = __builtin_amdgcn_mfma_f32_16x16x32_bf16(a[f*2+1], b0[n*2+1], acc[4+f][n], 0, 0, 0);
            }
        __builtin_amdgcn_s_setprio(0);
        if (T < NT - 2) { asm volatile("s_waitcnt vmcnt(4)" ::: "memory"); }
        else            { asm volatile("s_waitcnt vmcnt(0)" ::: "memory"); }
        __builtin_amdgcn_s_barrier();
    }
#undef STG_A
#undef STG_B

    // ---------- epilogue: 4 scratch regions, 4 frags per barrier pair ----------
    const int which = n0 >> 10;                       // block-uniform: q/k/v
    __bf16* op = (which == 0) ? qout : (which == 1) ? kout : vout;
    const float scl = (which == 0) ? QSCALE : 1.0f;
    __bf16* const eb0 = &As[0][0];                    // flat 32768 els
    __bf16* const eb1 = &Bs[0][0];                    // flat 32768 els
    const int rr = tid >> 4, cc = tid & 15;
#pragma unroll
    for (int f4 = 0; f4 < 2; ++f4) {
        __syncthreads();
#pragma unroll
        for (int j4 = 0; j4 < 4; ++j4) {
            const int f = f4 * 4 + j4;
            __bf16* rg = ((j4 & 2) ? eb1 : eb0) + (j4 & 1) * 8448;
#pragma unroll
            for (int n = 0; n < 4; ++n) {
                const int col = (n & 1) * 64 + wc * 16 + (n >> 1) * 128 + l15;
#pragma unroll
                for (int r = 0; r < 4; ++r)
                    rg[(wr * 16 + quad * 4 + r) * 264 + col] = (__bf16)(acc[f][n][r] * scl);
            }
        }
        __syncthreads();
#pragma unroll
        for (int j4 = 0; j4 < 4; ++j4) {
            const int f = f4 * 4 + j4;
            const __bf16* rg = ((j4 & 2) ? eb1 : eb0) + (j4 & 1) * 8448;
            const int m = m0 + (f & 3) * 32 + (f >> 2) * 128 + rr;
            if (m < Mreal) {
                const int b = m / T_REAL;
                const int t = m - b * T_REAL;
#pragma unroll
                for (int g = 0; g < 2; ++g) {
                    const int c8 = (cc + g * 16) * 8;
                    bf16x8 vv = *(const bf16x8*)&rg[rr * 264 + c8];
                    const int gc = n0 + c8;
                    const int h = (gc >> 6) & 15;
                    *(bf16x8*)&op[((size_t)(b * 16 + h) * Tp + t) * 64 + (gc & 63)] = vv;
                }
            }
        }
    }
}

// ---------------- 128x128x64 bf16 GEMM, f32 epilogue (projection) ----------------
template <int EPI>
__global__ __launch_bounds__(256)
void gemm128(const __bf16* __restrict__ A, const __bf16* __restrict__ Bt,
             float* __restrict__ outp,
             __bf16* __restrict__ qout, __bf16* __restrict__ kout,
             __bf16* __restrict__ vout) {
    __shared__ __bf16 As[128 * 64];   // 16 KB
    __shared__ __bf16 Bs[128 * 64];   // 16 KB

    const int tid = threadIdx.x, lane = tid & 63, w = tid >> 6;
    const int wr = w >> 1, wc = w & 1;
    const int quad = lane >> 4, l15 = lane & 15, l7 = l15 & 7;
    const int m0 = blockIdx.y * 128, n0 = blockIdx.x * 128;

    const int row0 = w * 32 + (lane >> 3);
    const int gc8 = ((lane & 7) ^ ((lane >> 3) & 7)) * 8;
    const __bf16* agp = A + (size_t)(m0 + row0) * GK + gc8;
    const __bf16* bgp = Bt + (size_t)(n0 + row0) * GK + gc8;
    __bf16* lap = &As[(w * 256 + lane) * 8];
    __bf16* lbp = &Bs[(w * 256 + lane) * 8];

    f32x4 acc[4][4] = {};

    for (int k0 = 0; k0 < GK; k0 += 64) {
#pragma unroll
        for (int s = 0; s < 4; s++) {
            GLDS(agp + (size_t)s * 8 * GK + k0, lap + s * 512);
            GLDS(bgp + (size_t)s * 8 * GK + k0, lbp + s * 512);
        }
        __syncthreads();
#pragma unroll
        for (int kk = 0; kk < 2; kk++) {
            bf16x8 fa[4], fb[4];
#pragma unroll
            for (int i = 0; i < 4; i++)
                fa[i] = *(const bf16x8*)&As[(wr * 64 + i * 16 + l15) * 64 + (((kk * 4 + quad) ^ l7) * 8)];
#pragma unroll
            for (int j = 0; j < 4; j++)
                fb[j] = *(const bf16x8*)&Bs[(wc * 64 + j * 16 + l15) * 64 + (((kk * 4 + quad) ^ l7) * 8)];
#pragma unroll
            for (int i = 0; i < 4; i++)
#pragma unroll
                for (int j = 0; j < 4; j++)
                    acc[i][j] = __builtin_amdgcn_mfma_f32_16x16x32_bf16(fa[i], fb[j], acc[i][j], 0, 0, 0);
        }
        __syncthreads();
    }

    if constexpr (EPI == 0) {
        const int which = n0 >> 10;
        const int h = ((n0 + wc * 64) >> 6) & 15;
        __bf16* op = (which == 0) ? qout : (which == 1) ? kout : vout;
        const float scl = (which == 0) ? QSCALE : 1.0f;
        __bf16* wls = &As[w * 2048];
#pragma unroll
        for (int p = 0; p < 2; p++) {
            if (p) __syncthreads();
#pragma unroll
            for (int i2 = 0; i2 < 2; i2++)
#pragma unroll
                for (int j = 0; j < 4; j++)
#pragma unroll
                    for (int r = 0; r < 4; r++) {
                        const int lrow = i2 * 16 + quad * 4 + r;
                        const int cX = (j * 2 + (l15 >> 3)) ^ (lrow & 7);
                        wls[lrow * 64 + cX * 8 + (l15 & 7)] =
                            (__bf16)(acc[p * 2 + i2][j][r] * scl);
                    }
            __syncthreads();
#pragma unroll
            for (int it = 0; it < 4; it++) {
                const int lrow = (lane >> 3) + it * 8;
                bf16x8 vv = *(const bf16x8*)&wls[lrow * 64 + (((lane & 7) ^ (lrow & 7)) * 8)];
                const int m = m0 + wr * 64 + p * 32 + lrow;
                if (m < Mreal) {
                    const int b = m / T_REAL;
                    const int t = m - b * T_REAL;
                    *(bf16x8*)&op[(((size_t)(b * 16 + h)) * Tp + t) * 64 + (lane & 7) * 8] = vv;
                }
            }
        }
    } else {
        float* wlf = (float*)&As[0] + w * 1024;
#pragma unroll
        for (int p = 0; p < 4; p++) {
            if (p) __syncthreads();
#pragma unroll
            for (int j = 0; j < 4; j++)
#pragma unroll
                for (int r = 0; r < 4; r++) {
                    const int lrow = quad * 4 + r;
                    const int cX = (j * 4 + (l15 >> 2)) ^ (lrow & 7);
                    wlf[lrow * 64 + cX * 4 + (l15 & 3)] = acc[p][j][r];
                }
            __syncthreads();
#pragma unroll
            for (int it = 0; it < 4; it++) {
                const int lrow = lane >> 2;
                const int c = (lane & 3) + it * 4;
                f32x4 vv = *(const f32x4*)&wlf[lrow * 64 + ((c ^ (lrow & 7)) * 4)];
                const int m = m0 + wr * 64 + p * 16 + lrow;
                if (m < Mreal)
                    *(f32x4*)&outp[(size_t)m * 1024 + n0 + wc * 64 + c * 4] = vv;
            }
        }
    }
}

// ---------------- flash attention v12: v11 + tree reductions + T5 + slot0 skip -
// v11 base (2-deep counted-vmcnt pipeline, 73->70us). This round:
//  * pairwise-tree max/sum reductions (serial 31-deep fp chains -> depth ~5;
//    max reorder is exact, sum reorder rounding-benign for bf16 output)
//  * myNt=0 for the qt==0 high-half wave (qg in [32,63] needs only tile 0;
//    was running 32 dead iterations on the LONGEST blocks)
//  * s_setprio(1) around QK and PV MFMA clusters (T5; multi-block phase
//    diversity exists here, unlike the lockstep GEMM case)
__global__ __launch_bounds__(256, 4)
void attn(const __bf16* __restrict__ q, const __bf16* __restrict__ kk,
          const __bf16* __restrict__ vT, __bf16* __restrict__ y) {
    __shared__ __bf16 Ks[2][64 * 64];     // 16 KB
    __shared__ __bf16 Vs[2][64 * 64];     // 16 KB  [d][kv]

    static const int QA[17] = {0,31,29,27,25,23,21,19,17,15,13,11,9,7,5,3,1};
    static const int QB[17] = {32,30,28,26,24,22,20,18,16,14,12,10,8,6,4,2,-1};

    const int tid = threadIdx.x, lane = tid & 63, w = tid >> 6;
    const int l31 = lane & 31, hi = lane >> 5, l7 = l31 & 7;
    const int z = blockIdx.x;
    const int slot = z >> 6, zz = z & 63;
    const int bh = (zz & 7) * 8 + (zz >> 3);

    const int qtA = QA[slot];
    const int qt = (w < 2) ? qtA : QB[slot];       // waves 0-1 -> A, 2-3 -> B
    const bool active = qt >= 0;
    const int qts = active ? qt : 0;
    const int qg = qts * 64 + (w & 1) * 32 + l31;  // this lane's q-row
    // qt==0 high-half wave (qg 32..63): only kv-tile 0 is live (no qg==0 row)
    const int myNt = (qts == 0) ? ((w & 1) ? 0 : 32) : qts;
    const int ntmaxB = (qtA == 0) ? 32 : qtA;      // >= 1 always

    const __bf16* kgb = kk + (size_t)bh * Tp * 64;
    const __bf16* vgb = vT + (size_t)bh * 64 * Tp;
    const int b = bh >> 4, h = bh & 15;

    // staging: per wave 2 K-GLDS + 2 V-GLDS, each covers 8 rows x 64 cols.
    const int sr = lane >> 3;                      // row-in-group 0..7
    const int scol = ((lane & 7) ^ sr) * 8;        // swizzled source chunk
    const int rk = w * 16 + sr;                    // source row (+8 for i=1)
    const int ldk = w * 1024 + lane * 8;           // LDS dest element (+512 i=1)

    bf16x8 qa[4];
    {
        const __bf16* qp = q + ((size_t)bh * Tp + qg) * 64 + hi * 8;
#pragma unroll
        for (int s = 0; s < 4; ++s) qa[s] = *(const bf16x8*)(qp + s * 16);
    }

    f32x16 o0 = {}, o1 = {};         // O^T: col=q, row d = (t&3)+8(t>>2)+4hi (+32 for o1)
    float mrow = -3e38f, lrow = 0.f;

    // prologue: stage tiles 0 and 1 (ntmaxB >= 1 always)
#define STG_KV(NT_, BUF_) do { \
    const size_t ko_ = (size_t)(NT_) * 4096, vo_ = (size_t)(NT_) * 64; \
    GLDS(kgb + ko_ + rk * 64 + scol,               &Ks[BUF_][ldk]); \
    GLDS(kgb + ko_ + (rk + 8) * 64 + scol,         &Ks[BUF_][ldk + 512]); \
    GLDS(vgb + vo_ + (size_t)rk * Tp + scol,       &Vs[BUF_][ldk]); \
    GLDS(vgb + vo_ + (size_t)(rk + 8) * Tp + scol, &Vs[BUF_][ldk + 512]); } while (0)

    STG_KV(0, 0);
    STG_KV(1, 1);

#pragma unroll 1
    for (int nt = 0; nt <= ntmaxB; ++nt) {
        const int cur = nt & 1;
        // tile nt ready; leave tile nt+1's 4 loads in flight (never drain mid-loop)
        if (nt < ntmaxB) { asm volatile("s_waitcnt vmcnt(4)" ::: "memory"); }
        else             { asm volatile("s_waitcnt vmcnt(0)" ::: "memory"); }
        __builtin_amdgcn_s_barrier();
        asm volatile("" ::: "memory");

        if (active && nt <= myNt) {
            const int kv0 = nt * 64;

            // S^T = K * Q^T : two 32-kv blocks, K=64 in 4 slices of 16
            f32x16 s0 = {}, s1 = {};
            __builtin_amdgcn_s_setprio(1);
#pragma unroll
            for (int sl = 0; sl < 4; ++sl) {
                const int ch = ((sl * 2 + hi) ^ l7) * 8;
                bf16x8 k0 = *(const bf16x8*)&Ks[cur][l31 * 64 + ch];
                bf16x8 k1 = *(const bf16x8*)&Ks[cur][(32 + l31) * 64 + ch];
                s0 = __builtin_amdgcn_mfma_f32_32x32x16_bf16(k0, qa[sl], s0, 0, 0, 0);
                s1 = __builtin_amdgcn_mfma_f32_32x32x16_bf16(k1, qa[sl], s1, 0, 0, 0);
            }
            __builtin_amdgcn_s_setprio(0);

            if (nt >= qts) {   // mask only on/past the diagonal (wave-uniform)
#pragma unroll
                for (int t = 0; t < 16; ++t) {
                    const int kvg = kv0 + (t & 3) + 8 * (t >> 2) + 4 * hi;
                    const bool v0 = (kvg <= qg) || (qg == 0 && kvg < T_REAL);
                    const bool v1 = (kvg + 32 <= qg) || (qg == 0 && kvg + 32 < T_REAL);
                    s0[t] = v0 ? s0[t] : -1e30f;
                    s1[t] = v1 ? s1[t] : -1e30f;
                }
            }

            // online softmax (exp2 domain); lane pair (l, l+32) shares one q-row
            // pairwise-tree max: depth ~5 instead of a 31-deep serial chain
            float tm[8];
#pragma unroll
            for (int t = 0; t < 8; ++t)
                tm[t] = fmaxf(fmaxf(s0[t], s1[t]), fmaxf(s0[t + 8], s1[t + 8]));
#pragma unroll
            for (int st = 4; st > 0; st >>= 1)
#pragma unroll
                for (int t = 0; t < st; ++t) tm[t] = fmaxf(tm[t], tm[t + st]);
            float mx = fmaxf(tm[0], __shfl_xor(tm[0], 32));
            if (!__all(mx - mrow <= 8.0f)) {      // T13 defer-max
                const float mn = fmaxf(mrow, mx);
                const float alpha = __builtin_amdgcn_exp2f(mrow - mn);
                mrow = mn;
                lrow *= alpha;
#pragma unroll
                for (int t = 0; t < 16; ++t) { o0[t] *= alpha; o1[t] *= alpha; }
            }

            float tr[8];
#pragma unroll
            for (int t = 0; t < 8; ++t) {
                s0[t]     = __builtin_amdgcn_exp2f(s0[t] - mrow);
                s1[t]     = __builtin_amdgcn_exp2f(s1[t] - mrow);
                s0[t + 8] = __builtin_amdgcn_exp2f(s0[t + 8] - mrow);
                s1[t + 8] = __builtin_amdgcn_exp2f(s1[t + 8] - mrow);
                tr[t] = (s0[t] + s1[t]) + (s0[t + 8] + s1[t + 8]);
            }
#pragma unroll
            for (int st = 4; st > 0; st >>= 1)
#pragma unroll
                for (int t = 0; t < st; ++t) tr[t] += tr[t + st];
            lrow += tr[0] + __shfl_xor(tr[0], 32);

            // P B-frags in registers (T12) + PV
            __builtin_amdgcn_s_setprio(1);
#pragma unroll
            for (int m = 0; m < 4; ++m) {
                const f32x16 sb = (m & 2) ? s1 : s0;
                constexpr int SB8[4] = {0, 8, 0, 8};
                const int s8 = SB8[m];
                unsigned a01, a23, a45, a67;
                asm("v_cvt_pk_bf16_f32 %0, %1, %2" : "=v"(a01) : "v"(sb[s8 + 0]), "v"(sb[s8 + 1]));
                asm("v_cvt_pk_bf16_f32 %0, %1, %2" : "=v"(a23) : "v"(sb[s8 + 2]), "v"(sb[s8 + 3]));
                asm("v_cvt_pk_bf16_f32 %0, %1, %2" : "=v"(a45) : "v"(sb[s8 + 4]), "v"(sb[s8 + 5]));
                asm("v_cvt_pk_bf16_f32 %0, %1, %2" : "=v"(a67) : "v"(sb[s8 + 6]), "v"(sb[s8 + 7]));
                asm("v_permlane32_swap_b32 %0, %1" : "+v"(a01), "+v"(a45));
                asm("v_permlane32_swap_b32 %0, %1" : "+v"(a23), "+v"(a67));
                union { unsigned u[4]; bf16x8 v; } pf;
                pf.u[0] = a01; pf.u[1] = a23; pf.u[2] = a45; pf.u[3] = a67;
                const int ch = ((m * 2 + hi) ^ l7) * 8;
                bf16x8 v0 = *(const bf16x8*)&Vs[cur][l31 * 64 + ch];
                bf16x8 v1 = *(const bf16x8*)&Vs[cur][(32 + l31) * 64 + ch];
                o0 = __builtin_amdgcn_mfma_f32_32x32x16_bf16(v0, pf.v, o0, 0, 0, 0);
                o1 = __builtin_amdgcn_mfma_f32_32x32x16_bf16(v1, pf.v, o1, 0, 0, 0);
            }
            __builtin_amdgcn_s_setprio(0);
        }

        // all waves done reading buf[cur]; then refill it with tile nt+2
        asm volatile("" ::: "memory");
        __builtin_amdgcn_s_barrier();
        asm volatile("" ::: "memory");
        if (nt + 2 <= ntmaxB) STG_KV(nt + 2, cur);
    }
#undef STG_KV

    // y[b, t=qg, h*64 + d], d = g*8 + hi*4 + j (+32 for o1); packed 8B stores
    if (active && qg < T_REAL) {
        const float inv = 1.0f / lrow;
        __bf16* yp = y + ((size_t)(b * T_REAL + qg)) * 1024 + h * 64 + hi * 4;
#pragma unroll
        for (int g = 0; g < 4; ++g) {
            bf16x4 w0, w1;
            w0.x = (__bf16)(o0[g * 4 + 0] * inv);
            w0.y = (__bf16)(o0[g * 4 + 1] * inv);
            w0.z = (__bf16)(o0[g * 4 + 2] * inv);
            w0.w = (__bf16)(o0[g * 4 + 3] * inv);
            w1.x = (__bf16)(o1[g * 4 + 0] * inv);
            w1.y = (__bf16)(o1[g * 4 + 1] * inv);
            w1.z = (__bf16)(o1[g * 4 + 2] * inv);
            w1.w = (__bf16)(o1[g * 4 + 3] * inv);
            *(bf16x4*)(yp + g * 8)      = w0;
            *(bf16x4*)(yp + 32 + g * 8) = w1;
        }
    }
}

// ---------------- launch ----------------
extern "C" void kernel_launch(void* const* d_in, const int* in_sizes, int n_in,
                              void* d_out, int out_size, void* d_ws, size_t ws_size,
                              hipStream_t stream) {
    const float* x  = (const float*)d_in[0];
    const float* Wa = (const float*)d_in[1];
    const float* Wp = (const float*)d_in[2];
    float* out = (float*)d_out;

    char* ws = (char*)d_ws;
    constexpr size_t SZ_XB  = (size_t)Mp * GK * 2;
    constexpr size_t SZ_WAT = (size_t)3072 * GK * 2;
    constexpr size_t SZ_WPT = (size_t)1024 * GK * 2;
    constexpr size_t SZ_QK  = (size_t)64 * Tp * 64 * 2;
    __bf16* xb   = (__bf16*)(ws);
    __bf16* WaT  = (__bf16*)(ws + SZ_XB);
    __bf16* WpT  = (__bf16*)(ws + SZ_XB + SZ_WAT);
    __bf16* qb   = (__bf16*)(ws + SZ_XB + SZ_WAT + SZ_WPT);
    __bf16* kb   = (__bf16*)(ws + SZ_XB + SZ_WAT + SZ_WPT + SZ_QK);
    __bf16* vTb  = (__bf16*)(ws + SZ_XB + SZ_WAT + SZ_WPT + 2 * SZ_QK);
    __bf16* shrd = (__bf16*)(ws + SZ_XB + SZ_WAT + SZ_WPT + 3 * SZ_QK);
    __bf16* vpre = shrd;   // v [bh][t][d], consumed by transpose_v before attn
    __bf16* yb   = shrd;   // attn output, written after vpre is dead

    prep<<<9472, 256, 0, stream>>>(x, xb, Wa, WaT, Wp, WpT);
    gemm256<<<dim3(12, 33), 512, 0, stream>>>(xb, WaT, qb, kb, vpre);
    transpose_v<<<dim3(33, 64), 256, 0, stream>>>(vpre, vTb);
    attn<<<1088, 256, 0, stream>>>(qb, kb, vTb, yb);
    gemm128<1><<<dim3(8, 65), 256, 0, stream>>>(yb, WpT, out, nullptr, nullptr, nullptr);
}

// Round 10
// 274.265 us; speedup vs baseline: 1.0157x; 1.0157x over previous
//
#include <hip/hip_runtime.h>

typedef __attribute__((ext_vector_type(8))) __bf16 bf16x8;
typedef __attribute__((ext_vector_type(4))) __bf16 bf16x4;
typedef __attribute__((ext_vector_type(4))) float f32x4;
typedef __attribute__((ext_vector_type(16))) float f32x16;

#define GLDS(g, l) __builtin_amdgcn_global_load_lds( \
    (__attribute__((address_space(1))) void*)(void*)(g), \
    (__attribute__((address_space(3))) void*)(void*)(l), 16, 0, 0)

constexpr int T_REAL = 2049;   // sequence length
constexpr int Tp     = 2112;   // padded to 33*64
constexpr int Mreal  = 8196;   // 4*2049
constexpr int Mp     = 8448;   // padded to 33*256 (256-tile GEMM)
constexpr int GK     = 1024;   // C

// q pre-scale: 1/sqrt(64) * log2(e)  -> softmax runs in exp2 domain
constexpr float QSCALE = 0.125f * 1.4426950408889634f;

// ---------------- fused prep: cvt_x + transpose_w(Wa) + transpose_w(Wp) -------
__global__ __launch_bounds__(256)
void prep(const float* __restrict__ x, __bf16* __restrict__ xb,
          const float* __restrict__ Wa, __bf16* __restrict__ WaT,
          const float* __restrict__ Wp, __bf16* __restrict__ WpT) {
    __shared__ float tile[64][65];
    const int z = blockIdx.x;
    if (z < 8448) {               // ---- cvt_x: fp32 -> bf16, zero-pad rows ----
        size_t i = ((size_t)z * 256 + threadIdx.x) * 4;
        float4 v = make_float4(0.f, 0.f, 0.f, 0.f);
        if (i < (size_t)Mreal * GK) v = *(const float4*)(x + i);
        bf16x4 o;
        o.x = (__bf16)v.x; o.y = (__bf16)v.y; o.z = (__bf16)v.z; o.w = (__bf16)v.w;
        *(bf16x4*)(xb + i) = o;
        return;
    }
    const float* W; __bf16* Wt; int N, idx;
    if (z < 9216) { W = Wa; Wt = WaT; N = 3072; idx = z - 8448; }
    else          { W = Wp; Wt = WpT; N = 1024; idx = z - 9216; }
    const int ntiles = N >> 6;
    const int n0 = (idx % ntiles) * 64, k0 = (idx / ntiles) * 64;
    const int tx = threadIdx.x & 63, ty = threadIdx.x >> 6;
#pragma unroll
    for (int j = 0; j < 16; j++) {
        int rk = ty + j * 4;
        tile[rk][tx] = W[(size_t)(k0 + rk) * N + n0 + tx];
    }
    __syncthreads();
#pragma unroll
    for (int j = 0; j < 16; j++) {
        int rn = ty + j * 4;
        Wt[(size_t)(n0 + rn) * GK + k0 + tx] = (__bf16)tile[tx][rn];
    }
}

// ---------------- transpose v: [bh][t][d] -> [bh][d][t] ----------------
__global__ __launch_bounds__(256) void transpose_v(const __bf16* __restrict__ v,
                                                   __bf16* __restrict__ vT) {
    __shared__ __bf16 tl[64][72];   // stride 72 els = 144B rows, 16B-aligned
    const int bh = blockIdx.y, t0 = blockIdx.x * 64;
    const int tid = threadIdx.x;
    const __bf16* src = v + ((size_t)bh * Tp + t0) * 64;
    {
        const int r = tid >> 3, c = (tid & 7) * 8;
        *(bf16x8*)&tl[r][c]      = *(const bf16x8*)(src + r * 64 + c);
        *(bf16x8*)&tl[r + 32][c] = *(const bf16x8*)(src + (r + 32) * 64 + c);
    }
    __syncthreads();
    __bf16* dst = vT + (size_t)bh * 64 * Tp + t0;
    {
        const int d = tid >> 3, tc = (tid & 7) * 8;
        bf16x8 a, b;
#pragma unroll
        for (int i = 0; i < 8; i++) {
            a[i] = tl[tc + i][d];
            b[i] = tl[tc + i][d + 32];
        }
        *(bf16x8*)(dst + (size_t)d * Tp + tc)        = a;
        *(bf16x8*)(dst + (size_t)(d + 32) * Tp + tc) = b;
    }
}

// ---------------- 256x256x64 8-phase pipelined QKV GEMM (round-8 version) -----
// Round-9's 4-region/4-barrier epilogue regressed 75.4 -> 84.6us (A/B over 5
// dispatches) -- reverted to the per-fragment 16-barrier epilogue. Barrier
// count was not the cost; the 4x store burst per window was.
__global__ __launch_bounds__(512)
void gemm256(const __bf16* __restrict__ A, const __bf16* __restrict__ Bt,
             __bf16* __restrict__ qout, __bf16* __restrict__ kout,
             __bf16* __restrict__ vout) {
    __shared__ __align__(16) __bf16 As[2][16384];   // 2 x 32 KB
    __shared__ __align__(16) __bf16 Bs[2][16384];   // 2 x 32 KB

    const int tid = threadIdx.x, lane = tid & 63, w = tid >> 6;
    const int wr = w >> 2, wc = w & 3;
    const int quad = lane >> 4, l15 = lane & 15, l7 = l15 & 7;
    const int m0 = blockIdx.y * 256, n0 = blockIdx.x * 256;

    const int sr = tid >> 3;                       // 0..63
    const int sc = ((tid & 7) ^ (sr & 7)) * 8;
    const __bf16* ag = A  + (size_t)(m0 + sr) * GK + sc;
    const __bf16* bg = Bt + (size_t)(n0 + sr) * GK + sc;
    const int ldst = tid * 8;

#define STG_A(T, h) do { const __bf16* s_ = ag + (size_t)(h) * 128 * GK + (T) * 64; \
    GLDS(s_, &As[(T) & 1][(h) * 8192 + ldst]); \
    GLDS(s_ + (size_t)64 * GK, &As[(T) & 1][(h) * 8192 + 4096 + ldst]); } while (0)
#define STG_B(T, h) do { const __bf16* s_ = bg + (size_t)(h) * 128 * GK + (T) * 64; \
    GLDS(s_, &Bs[(T) & 1][(h) * 8192 + ldst]); \
    GLDS(s_ + (size_t)64 * GK, &Bs[(T) & 1][(h) * 8192 + 4096 + ldst]); } while (0)

    f32x4 acc[8][4] = {};
    bf16x8 a[8], b0[4], b1[4];

    STG_A(0, 0); STG_B(0, 1); STG_A(0, 1); STG_B(0, 0); STG_A(1, 0); STG_B(1, 1);
    asm volatile("s_waitcnt vmcnt(4)" ::: "memory");
    __builtin_amdgcn_s_barrier();

    constexpr int NT = GK / 64;   // 16

#pragma unroll 1
    for (int T = 0; T < NT; ++T) {
        const int p = T & 1;

        // ---------- phase 1: read A0 + B0; stage A1/B0(T+1) ----------
#pragma unroll
        for (int f = 0; f < 4; ++f) {
            const int R = f * 32 + wr * 16 + l15;
            a[f * 2 + 0] = *(const bf16x8*)&As[p][R * 64 + ((quad ^ l7) * 8)];
            a[f * 2 + 1] = *(const bf16x8*)&As[p][R * 64 + (((4 + quad) ^ l7) * 8)];
        }
#pragma unroll
        for (int n = 0; n < 2; ++n) {
            const int R = n * 64 + wc * 16 + l15;
            b0[n * 2 + 0] = *(const bf16x8*)&Bs[p][R * 64 + ((quad ^ l7) * 8)];
            b0[n * 2 + 1] = *(const bf16x8*)&Bs[p][R * 64 + (((4 + quad) ^ l7) * 8)];
        }
        if (T + 1 < NT) { STG_A(T + 1, 1); STG_B(T + 1, 0); }
        __builtin_amdgcn_s_barrier();
        asm volatile("s_waitcnt lgkmcnt(0)" ::: "memory");
        __builtin_amdgcn_sched_barrier(0);
        __builtin_amdgcn_s_setprio(1);
#pragma unroll
        for (int f = 0; f < 4; ++f)
#pragma unroll
            for (int n = 0; n < 2; ++n) {
                acc[f][n] = __builtin_amdgcn_mfma_f32_16x16x32_bf16(a[f*2+0], b0[n*2+0], acc[f][n], 0, 0, 0);
                acc[f][n] = __builtin_amdgcn_mfma_f32_16x16x32_bf16(a[f*2+1], b0[n*2+1], acc[f][n], 0, 0, 0);
            }
        __builtin_amdgcn_s_setprio(0);
        __builtin_amdgcn_s_barrier();

        // ---------- phase 2: read B1; MFMA m0-3 x n2-3 ----------
#pragma unroll
        for (int n = 0; n < 2; ++n) {
            const int R = 128 + n * 64 + wc * 16 + l15;
            b1[n * 2 + 0] = *(const bf16x8*)&Bs[p][R * 64 + ((quad ^ l7) * 8)];
            b1[n * 2 + 1] = *(const bf16x8*)&Bs[p][R * 64 + (((4 + quad) ^ l7) * 8)];
        }
        __builtin_amdgcn_s_barrier();
        asm volatile("s_waitcnt lgkmcnt(0)" ::: "memory");
        __builtin_amdgcn_sched_barrier(0);
        __builtin_amdgcn_s_setprio(1);
#pragma unroll
        for (int f = 0; f < 4; ++f)
#pragma unroll
            for (int n = 0; n < 2; ++n) {
                acc[f][2+n] = __builtin_amdgcn_mfma_f32_16x16x32_bf16(a[f*2+0], b1[n*2+0], acc[f][2+n], 0, 0, 0);
                acc[f][2+n] = __builtin_amdgcn_mfma_f32_16x16x32_bf16(a[f*2+1], b1[n*2+1], acc[f][2+n], 0, 0, 0);
            }
        __builtin_amdgcn_s_setprio(0);
        __builtin_amdgcn_s_barrier();

        // ---------- phase 3: read A1; stage A0(T+2); MFMA m4-7 x n2-3 ----------
#pragma unroll
        for (int f = 0; f < 4; ++f) {
            const int R = 128 + f * 32 + wr * 16 + l15;
            a[f * 2 + 0] = *(const bf16x8*)&As[p][R * 64 + ((quad ^ l7) * 8)];
            a[f * 2 + 1] = *(const bf16x8*)&As[p][R * 64 + (((4 + quad) ^ l7) * 8)];
        }
        if (T + 2 < NT) STG_A(T + 2, 0);
        __builtin_amdgcn_s_barrier();
        asm volatile("s_waitcnt lgkmcnt(0)" ::: "memory");
        __builtin_amdgcn_sched_barrier(0);
        __builtin_amdgcn_s_setprio(1);
#pragma unroll
        for (int f = 0; f < 4; ++f)
#pragma unroll
            for (int n = 0; n < 2; ++n) {
                acc[4+f][2+n] = __builtin_amdgcn_mfma_f32_16x16x32_bf16(a[f*2+0], b1[n*2+0], acc[4+f][2+n], 0, 0, 0);
                acc[4+f][2+n] = __builtin_amdgcn_mfma_f32_16x16x32_bf16(a[f*2+1], b1[n*2+1], acc[4+f][2+n], 0, 0, 0);
            }
        __builtin_amdgcn_s_setprio(0);
        __builtin_amdgcn_s_barrier();

        // ---------- phase 4: stage B1(T+2); MFMA m4-7 x n0-1; counted vmcnt ----------
        if (T + 2 < NT) STG_B(T + 2, 1);
        __builtin_amdgcn_s_barrier();
        asm volatile("s_waitcnt lgkmcnt(0)" ::: "memory");
        __builtin_amdgcn_sched_barrier(0);
        __builtin_amdgcn_s_setprio(1);
#pragma unroll
        for (int f = 0; f < 4; ++f)
#pragma unroll
            for (int n = 0; n < 2; ++n) {
                acc[4+f][n] = __builtin_amdgcn_mfma_f32_16x16x32_bf16(a[f*2+0], b0[n*2+0], acc[4+f][n], 0, 0, 0);
                acc[4+f][n] = __builtin_amdgcn_mfma_f32_16x16x32_bf16(a[f*2+1], b0[n*2+1], acc[4+f][n], 0, 0, 0);
            }
        __builtin_amdgcn_s_setprio(0);
        if (T < NT - 2) { asm volatile("s_waitcnt vmcnt(4)" ::: "memory"); }
        else            { asm volatile("s_waitcnt vmcnt(0)" ::: "memory"); }
        __builtin_amdgcn_s_barrier();
    }
#undef STG_A
#undef STG_B

    // ---------- epilogue: per-m-frag LDS transpose -> coalesced bf16x8 stores ----
    const int which = n0 >> 10;                       // block-uniform: q/k/v
    __bf16* op = (which == 0) ? qout : (which == 1) ? kout : vout;
    const float scl = (which == 0) ? QSCALE : 1.0f;
    __bf16* ep = &As[0][0];                           // 32 x 264 bf16 = 16.5 KB
    const int rr = tid >> 4, cc = tid & 15;
#pragma unroll
    for (int f = 0; f < 8; ++f) {
        __syncthreads();
#pragma unroll
        for (int n = 0; n < 4; ++n) {
            const int col = (n & 1) * 64 + wc * 16 + (n >> 1) * 128 + l15;
#pragma unroll
            for (int r = 0; r < 4; ++r)
                ep[(wr * 16 + quad * 4 + r) * 264 + col] = (__bf16)(acc[f][n][r] * scl);
        }
        __syncthreads();
        const int m = m0 + (f & 3) * 32 + (f >> 2) * 128 + rr;
        if (m < Mreal) {
            const int b = m / T_REAL;
            const int t = m - b * T_REAL;
#pragma unroll
            for (int g = 0; g < 2; ++g) {
                const int c8 = (cc + g * 16) * 8;
                bf16x8 vv = *(const bf16x8*)&ep[rr * 264 + c8];
                const int gc = n0 + c8;
                const int h = (gc >> 6) & 15;
                *(bf16x8*)&op[((size_t)(b * 16 + h) * Tp + t) * 64 + (gc & 63)] = vv;
            }
        }
    }
}

// ---------------- 128x128x64 bf16 GEMM, f32 epilogue (projection) ----------------
template <int EPI>
__global__ __launch_bounds__(256)
void gemm128(const __bf16* __restrict__ A, const __bf16* __restrict__ Bt,
             float* __restrict__ outp,
             __bf16* __restrict__ qout, __bf16* __restrict__ kout,
             __bf16* __restrict__ vout) {
    __shared__ __bf16 As[128 * 64];   // 16 KB
    __shared__ __bf16 Bs[128 * 64];   // 16 KB

    const int tid = threadIdx.x, lane = tid & 63, w = tid >> 6;
    const int wr = w >> 1, wc = w & 1;
    const int quad = lane >> 4, l15 = lane & 15, l7 = l15 & 7;
    const int m0 = blockIdx.y * 128, n0 = blockIdx.x * 128;

    const int row0 = w * 32 + (lane >> 3);
    const int gc8 = ((lane & 7) ^ ((lane >> 3) & 7)) * 8;
    const __bf16* agp = A + (size_t)(m0 + row0) * GK + gc8;
    const __bf16* bgp = Bt + (size_t)(n0 + row0) * GK + gc8;
    __bf16* lap = &As[(w * 256 + lane) * 8];
    __bf16* lbp = &Bs[(w * 256 + lane) * 8];

    f32x4 acc[4][4] = {};

    for (int k0 = 0; k0 < GK; k0 += 64) {
#pragma unroll
        for (int s = 0; s < 4; s++) {
            GLDS(agp + (size_t)s * 8 * GK + k0, lap + s * 512);
            GLDS(bgp + (size_t)s * 8 * GK + k0, lbp + s * 512);
        }
        __syncthreads();
#pragma unroll
        for (int kk = 0; kk < 2; kk++) {
            bf16x8 fa[4], fb[4];
#pragma unroll
            for (int i = 0; i < 4; i++)
                fa[i] = *(const bf16x8*)&As[(wr * 64 + i * 16 + l15) * 64 + (((kk * 4 + quad) ^ l7) * 8)];
#pragma unroll
            for (int j = 0; j < 4; j++)
                fb[j] = *(const bf16x8*)&Bs[(wc * 64 + j * 16 + l15) * 64 + (((kk * 4 + quad) ^ l7) * 8)];
#pragma unroll
            for (int i = 0; i < 4; i++)
#pragma unroll
                for (int j = 0; j < 4; j++)
                    acc[i][j] = __builtin_amdgcn_mfma_f32_16x16x32_bf16(fa[i], fb[j], acc[i][j], 0, 0, 0);
        }
        __syncthreads();
    }

    if constexpr (EPI == 0) {
        const int which = n0 >> 10;
        const int h = ((n0 + wc * 64) >> 6) & 15;
        __bf16* op = (which == 0) ? qout : (which == 1) ? kout : vout;
        const float scl = (which == 0) ? QSCALE : 1.0f;
        __bf16* wls = &As[w * 2048];
#pragma unroll
        for (int p = 0; p < 2; p++) {
            if (p) __syncthreads();
#pragma unroll
            for (int i2 = 0; i2 < 2; i2++)
#pragma unroll
                for (int j = 0; j < 4; j++)
#pragma unroll
                    for (int r = 0; r < 4; r++) {
                        const int lrow = i2 * 16 + quad * 4 + r;
                        const int cX = (j * 2 + (l15 >> 3)) ^ (lrow & 7);
                        wls[lrow * 64 + cX * 8 + (l15 & 7)] =
                            (__bf16)(acc[p * 2 + i2][j][r] * scl);
                    }
            __syncthreads();
#pragma unroll
            for (int it = 0; it < 4; it++) {
                const int lrow = (lane >> 3) + it * 8;
                bf16x8 vv = *(const bf16x8*)&wls[lrow * 64 + (((lane & 7) ^ (lrow & 7)) * 8)];
                const int m = m0 + wr * 64 + p * 32 + lrow;
                if (m < Mreal) {
                    const int b = m / T_REAL;
                    const int t = m - b * T_REAL;
                    *(bf16x8*)&op[(((size_t)(b * 16 + h)) * Tp + t) * 64 + (lane & 7) * 8] = vv;
                }
            }
        }
    } else {
        float* wlf = (float*)&As[0] + w * 1024;
#pragma unroll
        for (int p = 0; p < 4; p++) {
            if (p) __syncthreads();
#pragma unroll
            for (int j = 0; j < 4; j++)
#pragma unroll
                for (int r = 0; r < 4; r++) {
                    const int lrow = quad * 4 + r;
                    const int cX = (j * 4 + (l15 >> 2)) ^ (lrow & 7);
                    wlf[lrow * 64 + cX * 4 + (l15 & 3)] = acc[p][j][r];
                }
            __syncthreads();
#pragma unroll
            for (int it = 0; it < 4; it++) {
                const int lrow = lane >> 2;
                const int c = (lane & 3) + it * 4;
                f32x4 vv = *(const f32x4*)&wlf[lrow * 64 + ((c ^ (lrow & 7)) * 4)];
                const int m = m0 + wr * 64 + p * 16 + lrow;
                if (m < Mreal)
                    *(f32x4*)&outp[(size_t)m * 1024 + n0 + wc * 64 + c * 4] = vv;
            }
        }
    }
}

// ---------------- flash attention v12: v11 + tree reductions + T5 + slot0 skip -
// (unchanged from round 9 -- its changes were the winning side of that round)
__global__ __launch_bounds__(256, 4)
void attn(const __bf16* __restrict__ q, const __bf16* __restrict__ kk,
          const __bf16* __restrict__ vT, __bf16* __restrict__ y) {
    __shared__ __bf16 Ks[2][64 * 64];     // 16 KB
    __shared__ __bf16 Vs[2][64 * 64];     // 16 KB  [d][kv]

    static const int QA[17] = {0,31,29,27,25,23,21,19,17,15,13,11,9,7,5,3,1};
    static const int QB[17] = {32,30,28,26,24,22,20,18,16,14,12,10,8,6,4,2,-1};

    const int tid = threadIdx.x, lane = tid & 63, w = tid >> 6;
    const int l31 = lane & 31, hi = lane >> 5, l7 = l31 & 7;
    const int z = blockIdx.x;
    const int slot = z >> 6, zz = z & 63;
    const int bh = (zz & 7) * 8 + (zz >> 3);

    const int qtA = QA[slot];
    const int qt = (w < 2) ? qtA : QB[slot];       // waves 0-1 -> A, 2-3 -> B
    const bool active = qt >= 0;
    const int qts = active ? qt : 0;
    const int qg = qts * 64 + (w & 1) * 32 + l31;  // this lane's q-row
    // qt==0 high-half wave (qg 32..63): only kv-tile 0 is live (no qg==0 row)
    const int myNt = (qts == 0) ? ((w & 1) ? 0 : 32) : qts;
    const int ntmaxB = (qtA == 0) ? 32 : qtA;      // >= 1 always

    const __bf16* kgb = kk + (size_t)bh * Tp * 64;
    const __bf16* vgb = vT + (size_t)bh * 64 * Tp;
    const int b = bh >> 4, h = bh & 15;

    // staging: per wave 2 K-GLDS + 2 V-GLDS, each covers 8 rows x 64 cols.
    const int sr = lane >> 3;                      // row-in-group 0..7
    const int scol = ((lane & 7) ^ sr) * 8;        // swizzled source chunk
    const int rk = w * 16 + sr;                    // source row (+8 for i=1)
    const int ldk = w * 1024 + lane * 8;           // LDS dest element (+512 i=1)

    bf16x8 qa[4];
    {
        const __bf16* qp = q + ((size_t)bh * Tp + qg) * 64 + hi * 8;
#pragma unroll
        for (int s = 0; s < 4; ++s) qa[s] = *(const bf16x8*)(qp + s * 16);
    }

    f32x16 o0 = {}, o1 = {};         // O^T: col=q, row d = (t&3)+8(t>>2)+4hi (+32 for o1)
    float mrow = -3e38f, lrow = 0.f;

    // prologue: stage tiles 0 and 1 (ntmaxB >= 1 always)
#define STG_KV(NT_, BUF_) do { \
    const size_t ko_ = (size_t)(NT_) * 4096, vo_ = (size_t)(NT_) * 64; \
    GLDS(kgb + ko_ + rk * 64 + scol,               &Ks[BUF_][ldk]); \
    GLDS(kgb + ko_ + (rk + 8) * 64 + scol,         &Ks[BUF_][ldk + 512]); \
    GLDS(vgb + vo_ + (size_t)rk * Tp + scol,       &Vs[BUF_][ldk]); \
    GLDS(vgb + vo_ + (size_t)(rk + 8) * Tp + scol, &Vs[BUF_][ldk + 512]); } while (0)

    STG_KV(0, 0);
    STG_KV(1, 1);

#pragma unroll 1
    for (int nt = 0; nt <= ntmaxB; ++nt) {
        const int cur = nt & 1;
        // tile nt ready; leave tile nt+1's 4 loads in flight (never drain mid-loop)
        if (nt < ntmaxB) { asm volatile("s_waitcnt vmcnt(4)" ::: "memory"); }
        else             { asm volatile("s_waitcnt vmcnt(0)" ::: "memory"); }
        __builtin_amdgcn_s_barrier();
        asm volatile("" ::: "memory");

        if (active && nt <= myNt) {
            const int kv0 = nt * 64;

            // S^T = K * Q^T : two 32-kv blocks, K=64 in 4 slices of 16
            f32x16 s0 = {}, s1 = {};
            __builtin_amdgcn_s_setprio(1);
#pragma unroll
            for (int sl = 0; sl < 4; ++sl) {
                const int ch = ((sl * 2 + hi) ^ l7) * 8;
                bf16x8 k0 = *(const bf16x8*)&Ks[cur][l31 * 64 + ch];
                bf16x8 k1 = *(const bf16x8*)&Ks[cur][(32 + l31) * 64 + ch];
                s0 = __builtin_amdgcn_mfma_f32_32x32x16_bf16(k0, qa[sl], s0, 0, 0, 0);
                s1 = __builtin_amdgcn_mfma_f32_32x32x16_bf16(k1, qa[sl], s1, 0, 0, 0);
            }
            __builtin_amdgcn_s_setprio(0);

            if (nt >= qts) {   // mask only on/past the diagonal (wave-uniform)
#pragma unroll
                for (int t = 0; t < 16; ++t) {
                    const int kvg = kv0 + (t & 3) + 8 * (t >> 2) + 4 * hi;
                    const bool v0 = (kvg <= qg) || (qg == 0 && kvg < T_REAL);
                    const bool v1 = (kvg + 32 <= qg) || (qg == 0 && kvg + 32 < T_REAL);
                    s0[t] = v0 ? s0[t] : -1e30f;
                    s1[t] = v1 ? s1[t] : -1e30f;
                }
            }

            // online softmax (exp2 domain); lane pair (l, l+32) shares one q-row
            // pairwise-tree max: depth ~5 instead of a 31-deep serial chain
            float tm[8];
#pragma unroll
            for (int t = 0; t < 8; ++t)
                tm[t] = fmaxf(fmaxf(s0[t], s1[t]), fmaxf(s0[t + 8], s1[t + 8]));
#pragma unroll
            for (int st = 4; st > 0; st >>= 1)
#pragma unroll
                for (int t = 0; t < st; ++t) tm[t] = fmaxf(tm[t], tm[t + st]);
            float mx = fmaxf(tm[0], __shfl_xor(tm[0], 32));
            if (!__all(mx - mrow <= 8.0f)) {      // T13 defer-max
                const float mn = fmaxf(mrow, mx);
                const float alpha = __builtin_amdgcn_exp2f(mrow - mn);
                mrow = mn;
                lrow *= alpha;
#pragma unroll
                for (int t = 0; t < 16; ++t) { o0[t] *= alpha; o1[t] *= alpha; }
            }

            float tr[8];
#pragma unroll
            for (int t = 0; t < 8; ++t) {
                s0[t]     = __builtin_amdgcn_exp2f(s0[t] - mrow);
                s1[t]     = __builtin_amdgcn_exp2f(s1[t] - mrow);
                s0[t + 8] = __builtin_amdgcn_exp2f(s0[t + 8] - mrow);
                s1[t + 8] = __builtin_amdgcn_exp2f(s1[t + 8] - mrow);
                tr[t] = (s0[t] + s1[t]) + (s0[t + 8] + s1[t + 8]);
            }
#pragma unroll
            for (int st = 4; st > 0; st >>= 1)
#pragma unroll
                for (int t = 0; t < st; ++t) tr[t] += tr[t + st];
            lrow += tr[0] + __shfl_xor(tr[0], 32);

            // P B-frags in registers (T12) + PV
            __builtin_amdgcn_s_setprio(1);
#pragma unroll
            for (int m = 0; m < 4; ++m) {
                const f32x16 sb = (m & 2) ? s1 : s0;
                constexpr int SB8[4] = {0, 8, 0, 8};
                const int s8 = SB8[m];
                unsigned a01, a23, a45, a67;
                asm("v_cvt_pk_bf16_f32 %0, %1, %2" : "=v"(a01) : "v"(sb[s8 + 0]), "v"(sb[s8 + 1]));
                asm("v_cvt_pk_bf16_f32 %0, %1, %2" : "=v"(a23) : "v"(sb[s8 + 2]), "v"(sb[s8 + 3]));
                asm("v_cvt_pk_bf16_f32 %0, %1, %2" : "=v"(a45) : "v"(sb[s8 + 4]), "v"(sb[s8 + 5]));
                asm("v_cvt_pk_bf16_f32 %0, %1, %2" : "=v"(a67) : "v"(sb[s8 + 6]), "v"(sb[s8 + 7]));
                asm("v_permlane32_swap_b32 %0, %1" : "+v"(a01), "+v"(a45));
                asm("v_permlane32_swap_b32 %0, %1" : "+v"(a23), "+v"(a67));
                union { unsigned u[4]; bf16x8 v; } pf;
                pf.u[0] = a01; pf.u[1] = a23; pf.u[2] = a45; pf.u[3] = a67;
                const int ch = ((m * 2 + hi) ^ l7) * 8;
                bf16x8 v0 = *(const bf16x8*)&Vs[cur][l31 * 64 + ch];
                bf16x8 v1 = *(const bf16x8*)&Vs[cur][(32 + l31) * 64 + ch];
                o0 = __builtin_amdgcn_mfma_f32_32x32x16_bf16(v0, pf.v, o0, 0, 0, 0);
                o1 = __builtin_amdgcn_mfma_f32_32x32x16_bf16(v1, pf.v, o1, 0, 0, 0);
            }
            __builtin_amdgcn_s_setprio(0);
        }

        // all waves done reading buf[cur]; then refill it with tile nt+2
        asm volatile("" ::: "memory");
        __builtin_amdgcn_s_barrier();
        asm volatile("" ::: "memory");
        if (nt + 2 <= ntmaxB) STG_KV(nt + 2, cur);
    }
#undef STG_KV

    // y[b, t=qg, h*64 + d], d = g*8 + hi*4 + j (+32 for o1); packed 8B stores
    if (active && qg < T_REAL) {
        const float inv = 1.0f / lrow;
        __bf16* yp = y + ((size_t)(b * T_REAL + qg)) * 1024 + h * 64 + hi * 4;
#pragma unroll
        for (int g = 0; g < 4; ++g) {
            bf16x4 w0, w1;
            w0.x = (__bf16)(o0[g * 4 + 0] * inv);
            w0.y = (__bf16)(o0[g * 4 + 1] * inv);
            w0.z = (__bf16)(o0[g * 4 + 2] * inv);
            w0.w = (__bf16)(o0[g * 4 + 3] * inv);
            w1.x = (__bf16)(o1[g * 4 + 0] * inv);
            w1.y = (__bf16)(o1[g * 4 + 1] * inv);
            w1.z = (__bf16)(o1[g * 4 + 2] * inv);
            w1.w = (__bf16)(o1[g * 4 + 3] * inv);
            *(bf16x4*)(yp + g * 8)      = w0;
            *(bf16x4*)(yp + 32 + g * 8) = w1;
        }
    }
}

// ---------------- launch ----------------
extern "C" void kernel_launch(void* const* d_in, const int* in_sizes, int n_in,
                              void* d_out, int out_size, void* d_ws, size_t ws_size,
                              hipStream_t stream) {
    const float* x  = (const float*)d_in[0];
    const float* Wa = (const float*)d_in[1];
    const float* Wp = (const float*)d_in[2];
    float* out = (float*)d_out;

    char* ws = (char*)d_ws;
    constexpr size_t SZ_XB  = (size_t)Mp * GK * 2;
    constexpr size_t SZ_WAT = (size_t)3072 * GK * 2;
    constexpr size_t SZ_WPT = (size_t)1024 * GK * 2;
    constexpr size_t SZ_QK  = (size_t)64 * Tp * 64 * 2;
    __bf16* xb   = (__bf16*)(ws);
    __bf16* WaT  = (__bf16*)(ws + SZ_XB);
    __bf16* WpT  = (__bf16*)(ws + SZ_XB + SZ_WAT);
    __bf16* qb   = (__bf16*)(ws + SZ_XB + SZ_WAT + SZ_WPT);
    __bf16* kb   = (__bf16*)(ws + SZ_XB + SZ_WAT + SZ_WPT + SZ_QK);
    __bf16* vTb  = (__bf16*)(ws + SZ_XB + SZ_WAT + SZ_WPT + 2 * SZ_QK);
    __bf16* shrd = (__bf16*)(ws + SZ_XB + SZ_WAT + SZ_WPT + 3 * SZ_QK);
    __bf16* vpre = shrd;   // v [bh][t][d], consumed by transpose_v before attn
    __bf16* yb   = shrd;   // attn output, written after vpre is dead

    prep<<<9472, 256, 0, stream>>>(x, xb, Wa, WaT, Wp, WpT);
    gemm256<<<dim3(12, 33), 512, 0, stream>>>(xb, WaT, qb, kb, vpre);
    transpose_v<<<dim3(33, 64), 256, 0, stream>>>(vpre, vTb);
    attn<<<1088, 256, 0, stream>>>(qb, kb, vTb, yb);
    gemm128<1><<<dim3(8, 65), 256, 0, stream>>>(yb, WpT, out, nullptr, nullptr, nullptr);
}

// Round 11
// 272.002 us; speedup vs baseline: 1.0241x; 1.0083x over previous
//
#include <hip/hip_runtime.h>

typedef __attribute__((ext_vector_type(8))) __bf16 bf16x8;
typedef __attribute__((ext_vector_type(4))) __bf16 bf16x4;
typedef __attribute__((ext_vector_type(4))) float f32x4;
typedef __attribute__((ext_vector_type(16))) float f32x16;

#define GLDS(g, l) __builtin_amdgcn_global_load_lds( \
    (__attribute__((address_space(1))) void*)(void*)(g), \
    (__attribute__((address_space(3))) void*)(void*)(l), 16, 0, 0)

constexpr int T_REAL = 2049;   // sequence length
constexpr int Tp     = 2112;   // padded to 33*64
constexpr int Mreal  = 8196;   // 4*2049
constexpr int Mp     = 8448;   // padded to 33*256 (256-tile GEMM)
constexpr int GK     = 1024;   // C

// q pre-scale: 1/sqrt(64) * log2(e)  -> softmax runs in exp2 domain
constexpr float QSCALE = 0.125f * 1.4426950408889634f;

// ---------------- fused prep: cvt_x + transpose_w(Wa) + transpose_w(Wp) -------
__global__ __launch_bounds__(256)
void prep(const float* __restrict__ x, __bf16* __restrict__ xb,
          const float* __restrict__ Wa, __bf16* __restrict__ WaT,
          const float* __restrict__ Wp, __bf16* __restrict__ WpT) {
    __shared__ float tile[64][65];
    const int z = blockIdx.x;
    if (z < 8448) {               // ---- cvt_x: fp32 -> bf16, zero-pad rows ----
        size_t i = ((size_t)z * 256 + threadIdx.x) * 4;
        float4 v = make_float4(0.f, 0.f, 0.f, 0.f);
        if (i < (size_t)Mreal * GK) v = *(const float4*)(x + i);
        bf16x4 o;
        o.x = (__bf16)v.x; o.y = (__bf16)v.y; o.z = (__bf16)v.z; o.w = (__bf16)v.w;
        *(bf16x4*)(xb + i) = o;
        return;
    }
    const float* W; __bf16* Wt; int N, idx;
    if (z < 9216) { W = Wa; Wt = WaT; N = 3072; idx = z - 8448; }
    else          { W = Wp; Wt = WpT; N = 1024; idx = z - 9216; }
    const int ntiles = N >> 6;
    const int n0 = (idx % ntiles) * 64, k0 = (idx / ntiles) * 64;
    const int tx = threadIdx.x & 63, ty = threadIdx.x >> 6;
#pragma unroll
    for (int j = 0; j < 16; j++) {
        int rk = ty + j * 4;
        tile[rk][tx] = W[(size_t)(k0 + rk) * N + n0 + tx];
    }
    __syncthreads();
#pragma unroll
    for (int j = 0; j < 16; j++) {
        int rn = ty + j * 4;
        Wt[(size_t)(n0 + rn) * GK + k0 + tx] = (__bf16)tile[tx][rn];
    }
}

// ---------------- transpose v: [bh][t][d] -> [bh][d][t] ----------------
__global__ __launch_bounds__(256) void transpose_v(const __bf16* __restrict__ v,
                                                   __bf16* __restrict__ vT) {
    __shared__ __bf16 tl[64][72];   // stride 72 els = 144B rows, 16B-aligned
    const int bh = blockIdx.y, t0 = blockIdx.x * 64;
    const int tid = threadIdx.x;
    const __bf16* src = v + ((size_t)bh * Tp + t0) * 64;
    {
        const int r = tid >> 3, c = (tid & 7) * 8;
        *(bf16x8*)&tl[r][c]      = *(const bf16x8*)(src + r * 64 + c);
        *(bf16x8*)&tl[r + 32][c] = *(const bf16x8*)(src + (r + 32) * 64 + c);
    }
    __syncthreads();
    __bf16* dst = vT + (size_t)bh * 64 * Tp + t0;
    {
        const int d = tid >> 3, tc = (tid & 7) * 8;
        bf16x8 a, b;
#pragma unroll
        for (int i = 0; i < 8; i++) {
            a[i] = tl[tc + i][d];
            b[i] = tl[tc + i][d + 32];
        }
        *(bf16x8*)(dst + (size_t)d * Tp + tc)        = a;
        *(bf16x8*)(dst + (size_t)(d + 32) * Tp + tc) = b;
    }
}

// ---------------- 256x256x64 8-phase pipelined QKV GEMM (round-8 version) -----
__global__ __launch_bounds__(512)
void gemm256(const __bf16* __restrict__ A, const __bf16* __restrict__ Bt,
             __bf16* __restrict__ qout, __bf16* __restrict__ kout,
             __bf16* __restrict__ vout) {
    __shared__ __align__(16) __bf16 As[2][16384];   // 2 x 32 KB
    __shared__ __align__(16) __bf16 Bs[2][16384];   // 2 x 32 KB

    const int tid = threadIdx.x, lane = tid & 63, w = tid >> 6;
    const int wr = w >> 2, wc = w & 3;
    const int quad = lane >> 4, l15 = lane & 15, l7 = l15 & 7;
    const int m0 = blockIdx.y * 256, n0 = blockIdx.x * 256;

    const int sr = tid >> 3;                       // 0..63
    const int sc = ((tid & 7) ^ (sr & 7)) * 8;
    const __bf16* ag = A  + (size_t)(m0 + sr) * GK + sc;
    const __bf16* bg = Bt + (size_t)(n0 + sr) * GK + sc;
    const int ldst = tid * 8;

#define STG_A(T, h) do { const __bf16* s_ = ag + (size_t)(h) * 128 * GK + (T) * 64; \
    GLDS(s_, &As[(T) & 1][(h) * 8192 + ldst]); \
    GLDS(s_ + (size_t)64 * GK, &As[(T) & 1][(h) * 8192 + 4096 + ldst]); } while (0)
#define STG_B(T, h) do { const __bf16* s_ = bg + (size_t)(h) * 128 * GK + (T) * 64; \
    GLDS(s_, &Bs[(T) & 1][(h) * 8192 + ldst]); \
    GLDS(s_ + (size_t)64 * GK, &Bs[(T) & 1][(h) * 8192 + 4096 + ldst]); } while (0)

    f32x4 acc[8][4] = {};
    bf16x8 a[8], b0[4], b1[4];

    STG_A(0, 0); STG_B(0, 1); STG_A(0, 1); STG_B(0, 0); STG_A(1, 0); STG_B(1, 1);
    asm volatile("s_waitcnt vmcnt(4)" ::: "memory");
    __builtin_amdgcn_s_barrier();

    constexpr int NT = GK / 64;   // 16

#pragma unroll 1
    for (int T = 0; T < NT; ++T) {
        const int p = T & 1;

        // ---------- phase 1: read A0 + B0; stage A1/B0(T+1) ----------
#pragma unroll
        for (int f = 0; f < 4; ++f) {
            const int R = f * 32 + wr * 16 + l15;
            a[f * 2 + 0] = *(const bf16x8*)&As[p][R * 64 + ((quad ^ l7) * 8)];
            a[f * 2 + 1] = *(const bf16x8*)&As[p][R * 64 + (((4 + quad) ^ l7) * 8)];
        }
#pragma unroll
        for (int n = 0; n < 2; ++n) {
            const int R = n * 64 + wc * 16 + l15;
            b0[n * 2 + 0] = *(const bf16x8*)&Bs[p][R * 64 + ((quad ^ l7) * 8)];
            b0[n * 2 + 1] = *(const bf16x8*)&Bs[p][R * 64 + (((4 + quad) ^ l7) * 8)];
        }
        if (T + 1 < NT) { STG_A(T + 1, 1); STG_B(T + 1, 0); }
        __builtin_amdgcn_s_barrier();
        asm volatile("s_waitcnt lgkmcnt(0)" ::: "memory");
        __builtin_amdgcn_sched_barrier(0);
        __builtin_amdgcn_s_setprio(1);
#pragma unroll
        for (int f = 0; f < 4; ++f)
#pragma unroll
            for (int n = 0; n < 2; ++n) {
                acc[f][n] = __builtin_amdgcn_mfma_f32_16x16x32_bf16(a[f*2+0], b0[n*2+0], acc[f][n], 0, 0, 0);
                acc[f][n] = __builtin_amdgcn_mfma_f32_16x16x32_bf16(a[f*2+1], b0[n*2+1], acc[f][n], 0, 0, 0);
            }
        __builtin_amdgcn_s_setprio(0);
        __builtin_amdgcn_s_barrier();

        // ---------- phase 2: read B1; MFMA m0-3 x n2-3 ----------
#pragma unroll
        for (int n = 0; n < 2; ++n) {
            const int R = 128 + n * 64 + wc * 16 + l15;
            b1[n * 2 + 0] = *(const bf16x8*)&Bs[p][R * 64 + ((quad ^ l7) * 8)];
            b1[n * 2 + 1] = *(const bf16x8*)&Bs[p][R * 64 + (((4 + quad) ^ l7) * 8)];
        }
        __builtin_amdgcn_s_barrier();
        asm volatile("s_waitcnt lgkmcnt(0)" ::: "memory");
        __builtin_amdgcn_sched_barrier(0);
        __builtin_amdgcn_s_setprio(1);
#pragma unroll
        for (int f = 0; f < 4; ++f)
#pragma unroll
            for (int n = 0; n < 2; ++n) {
                acc[f][2+n] = __builtin_amdgcn_mfma_f32_16x16x32_bf16(a[f*2+0], b1[n*2+0], acc[f][2+n], 0, 0, 0);
                acc[f][2+n] = __builtin_amdgcn_mfma_f32_16x16x32_bf16(a[f*2+1], b1[n*2+1], acc[f][2+n], 0, 0, 0);
            }
        __builtin_amdgcn_s_setprio(0);
        __builtin_amdgcn_s_barrier();

        // ---------- phase 3: read A1; stage A0(T+2); MFMA m4-7 x n2-3 ----------
#pragma unroll
        for (int f = 0; f < 4; ++f) {
            const int R = 128 + f * 32 + wr * 16 + l15;
            a[f * 2 + 0] = *(const bf16x8*)&As[p][R * 64 + ((quad ^ l7) * 8)];
            a[f * 2 + 1] = *(const bf16x8*)&As[p][R * 64 + (((4 + quad) ^ l7) * 8)];
        }
        if (T + 2 < NT) STG_A(T + 2, 0);
        __builtin_amdgcn_s_barrier();
        asm volatile("s_waitcnt lgkmcnt(0)" ::: "memory");
        __builtin_amdgcn_sched_barrier(0);
        __builtin_amdgcn_s_setprio(1);
#pragma unroll
        for (int f = 0; f < 4; ++f)
#pragma unroll
            for (int n = 0; n < 2; ++n) {
                acc[4+f][2+n] = __builtin_amdgcn_mfma_f32_16x16x32_bf16(a[f*2+0], b1[n*2+0], acc[4+f][2+n], 0, 0, 0);
                acc[4+f][2+n] = __builtin_amdgcn_mfma_f32_16x16x32_bf16(a[f*2+1], b1[n*2+1], acc[4+f][2+n], 0, 0, 0);
            }
        __builtin_amdgcn_s_setprio(0);
        __builtin_amdgcn_s_barrier();

        // ---------- phase 4: stage B1(T+2); MFMA m4-7 x n0-1; counted vmcnt ----------
        if (T + 2 < NT) STG_B(T + 2, 1);
        __builtin_amdgcn_s_barrier();
        asm volatile("s_waitcnt lgkmcnt(0)" ::: "memory");
        __builtin_amdgcn_sched_barrier(0);
        __builtin_amdgcn_s_setprio(1);
#pragma unroll
        for (int f = 0; f < 4; ++f)
#pragma unroll
            for (int n = 0; n < 2; ++n) {
                acc[4+f][n] = __builtin_amdgcn_mfma_f32_16x16x32_bf16(a[f*2+0], b0[n*2+0], acc[4+f][n], 0, 0, 0);
                acc[4+f][n] = __builtin_amdgcn_mfma_f32_16x16x32_bf16(a[f*2+1], b0[n*2+1], acc[4+f][n], 0, 0, 0);
            }
        __builtin_amdgcn_s_setprio(0);
        if (T < NT - 2) { asm volatile("s_waitcnt vmcnt(4)" ::: "memory"); }
        else            { asm volatile("s_waitcnt vmcnt(0)" ::: "memory"); }
        __builtin_amdgcn_s_barrier();
    }
#undef STG_A
#undef STG_B

    // ---------- epilogue: per-m-frag LDS transpose -> coalesced bf16x8 stores ----
    const int which = n0 >> 10;                       // block-uniform: q/k/v
    __bf16* op = (which == 0) ? qout : (which == 1) ? kout : vout;
    const float scl = (which == 0) ? QSCALE : 1.0f;
    __bf16* ep = &As[0][0];                           // 32 x 264 bf16 = 16.5 KB
    const int rr = tid >> 4, cc = tid & 15;
#pragma unroll
    for (int f = 0; f < 8; ++f) {
        __syncthreads();
#pragma unroll
        for (int n = 0; n < 4; ++n) {
            const int col = (n & 1) * 64 + wc * 16 + (n >> 1) * 128 + l15;
#pragma unroll
            for (int r = 0; r < 4; ++r)
                ep[(wr * 16 + quad * 4 + r) * 264 + col] = (__bf16)(acc[f][n][r] * scl);
        }
        __syncthreads();
        const int m = m0 + (f & 3) * 32 + (f >> 2) * 128 + rr;
        if (m < Mreal) {
            const int b = m / T_REAL;
            const int t = m - b * T_REAL;
#pragma unroll
            for (int g = 0; g < 2; ++g) {
                const int c8 = (cc + g * 16) * 8;
                bf16x8 vv = *(const bf16x8*)&ep[rr * 264 + c8];
                const int gc = n0 + c8;
                const int h = (gc >> 6) & 15;
                *(bf16x8*)&op[((size_t)(b * 16 + h) * Tp + t) * 64 + (gc & 63)] = vv;
            }
        }
    }
}

// ---------------- 128x128x64 bf16 GEMM, f32 epilogue (projection) ----------------
template <int EPI>
__global__ __launch_bounds__(256)
void gemm128(const __bf16* __restrict__ A, const __bf16* __restrict__ Bt,
             float* __restrict__ outp,
             __bf16* __restrict__ qout, __bf16* __restrict__ kout,
             __bf16* __restrict__ vout) {
    __shared__ __bf16 As[128 * 64];   // 16 KB
    __shared__ __bf16 Bs[128 * 64];   // 16 KB

    const int tid = threadIdx.x, lane = tid & 63, w = tid >> 6;
    const int wr = w >> 1, wc = w & 1;
    const int quad = lane >> 4, l15 = lane & 15, l7 = l15 & 7;
    const int m0 = blockIdx.y * 128, n0 = blockIdx.x * 128;

    const int row0 = w * 32 + (lane >> 3);
    const int gc8 = ((lane & 7) ^ ((lane >> 3) & 7)) * 8;
    const __bf16* agp = A + (size_t)(m0 + row0) * GK + gc8;
    const __bf16* bgp = Bt + (size_t)(n0 + row0) * GK + gc8;
    __bf16* lap = &As[(w * 256 + lane) * 8];
    __bf16* lbp = &Bs[(w * 256 + lane) * 8];

    f32x4 acc[4][4] = {};

    for (int k0 = 0; k0 < GK; k0 += 64) {
#pragma unroll
        for (int s = 0; s < 4; s++) {
            GLDS(agp + (size_t)s * 8 * GK + k0, lap + s * 512);
            GLDS(bgp + (size_t)s * 8 * GK + k0, lbp + s * 512);
        }
        __syncthreads();
#pragma unroll
        for (int kk = 0; kk < 2; kk++) {
            bf16x8 fa[4], fb[4];
#pragma unroll
            for (int i = 0; i < 4; i++)
                fa[i] = *(const bf16x8*)&As[(wr * 64 + i * 16 + l15) * 64 + (((kk * 4 + quad) ^ l7) * 8)];
#pragma unroll
            for (int j = 0; j < 4; j++)
                fb[j] = *(const bf16x8*)&Bs[(wc * 64 + j * 16 + l15) * 64 + (((kk * 4 + quad) ^ l7) * 8)];
#pragma unroll
            for (int i = 0; i < 4; i++)
#pragma unroll
                for (int j = 0; j < 4; j++)
                    acc[i][j] = __builtin_amdgcn_mfma_f32_16x16x32_bf16(fa[i], fb[j], acc[i][j], 0, 0, 0);
        }
        __syncthreads();
    }

    if constexpr (EPI == 0) {
        const int which = n0 >> 10;
        const int h = ((n0 + wc * 64) >> 6) & 15;
        __bf16* op = (which == 0) ? qout : (which == 1) ? kout : vout;
        const float scl = (which == 0) ? QSCALE : 1.0f;
        __bf16* wls = &As[w * 2048];
#pragma unroll
        for (int p = 0; p < 2; p++) {
            if (p) __syncthreads();
#pragma unroll
            for (int i2 = 0; i2 < 2; i2++)
#pragma unroll
                for (int j = 0; j < 4; j++)
#pragma unroll
                    for (int r = 0; r < 4; r++) {
                        const int lrow = i2 * 16 + quad * 4 + r;
                        const int cX = (j * 2 + (l15 >> 3)) ^ (lrow & 7);
                        wls[lrow * 64 + cX * 8 + (l15 & 7)] =
                            (__bf16)(acc[p * 2 + i2][j][r] * scl);
                    }
            __syncthreads();
#pragma unroll
            for (int it = 0; it < 4; it++) {
                const int lrow = (lane >> 3) + it * 8;
                bf16x8 vv = *(const bf16x8*)&wls[lrow * 64 + (((lane & 7) ^ (lrow & 7)) * 8)];
                const int m = m0 + wr * 64 + p * 32 + lrow;
                if (m < Mreal) {
                    const int b = m / T_REAL;
                    const int t = m - b * T_REAL;
                    *(bf16x8*)&op[(((size_t)(b * 16 + h)) * Tp + t) * 64 + (lane & 7) * 8] = vv;
                }
            }
        }
    } else {
        float* wlf = (float*)&As[0] + w * 1024;
#pragma unroll
        for (int p = 0; p < 4; p++) {
            if (p) __syncthreads();
#pragma unroll
            for (int j = 0; j < 4; j++)
#pragma unroll
                for (int r = 0; r < 4; r++) {
                    const int lrow = quad * 4 + r;
                    const int cX = (j * 4 + (l15 >> 2)) ^ (lrow & 7);
                    wlf[lrow * 64 + cX * 4 + (l15 & 3)] = acc[p][j][r];
                }
            __syncthreads();
#pragma unroll
            for (int it = 0; it < 4; it++) {
                const int lrow = lane >> 2;
                const int c = (lane & 3) + it * 4;
                f32x4 vv = *(const f32x4*)&wlf[lrow * 64 + ((c ^ (lrow & 7)) * 4)];
                const int m = m0 + wr * 64 + p * 16 + lrow;
                if (m < Mreal)
                    *(f32x4*)&outp[(size_t)m * 1024 + n0 + wc * 64 + c * 4] = vv;
            }
        }
    }
}

// ---------------- flash attention v13: v12 + CU-class load balancing -----------
// Block cost varies 33..2 iters per 64-block slot-group. Under round-robin
// block->CU dispatch, CU class (group mod 4) previously summed {89,80,72,64}
// iters (descending slot order) -> makespan 89 vs ideal 76.25 (~17% tail-idle).
// GSL permutes slot->group so class sums become {75,76,76,78}. Pure reorder:
// correctness-neutral under any dispatch policy.
__global__ __launch_bounds__(256, 4)
void attn(const __bf16* __restrict__ q, const __bf16* __restrict__ kk,
          const __bf16* __restrict__ vT, __bf16* __restrict__ y) {
    __shared__ __bf16 Ks[2][64 * 64];     // 16 KB
    __shared__ __bf16 Vs[2][64 * 64];     // 16 KB  [d][kv]

    static const int QA[17] = {0,31,29,27,25,23,21,19,17,15,13,11,9,7,5,3,1};
    static const int QB[17] = {32,30,28,26,24,22,20,18,16,14,12,10,8,6,4,2,-1};
    // group -> slot: class sums (iters over groups g with g%4==c) balanced
    static const int GSL[17] = {0,1,2,4,3,7,6,5,13,8,10,9,15,14,12,11,16};

    const int tid = threadIdx.x, lane = tid & 63, w = tid >> 6;
    const int l31 = lane & 31, hi = lane >> 5, l7 = l31 & 7;
    const int z = blockIdx.x;
    const int slot = GSL[z >> 6], zz = z & 63;
    const int bh = (zz & 7) * 8 + (zz >> 3);

    const int qtA = QA[slot];
    const int qt = (w < 2) ? qtA : QB[slot];       // waves 0-1 -> A, 2-3 -> B
    const bool active = qt >= 0;
    const int qts = active ? qt : 0;
    const int qg = qts * 64 + (w & 1) * 32 + l31;  // this lane's q-row
    // qt==0 high-half wave (qg 32..63): only kv-tile 0 is live (no qg==0 row)
    const int myNt = (qts == 0) ? ((w & 1) ? 0 : 32) : qts;
    const int ntmaxB = (qtA == 0) ? 32 : qtA;      // >= 1 always

    const __bf16* kgb = kk + (size_t)bh * Tp * 64;
    const __bf16* vgb = vT + (size_t)bh * 64 * Tp;
    const int b = bh >> 4, h = bh & 15;

    // staging: per wave 2 K-GLDS + 2 V-GLDS, each covers 8 rows x 64 cols.
    const int sr = lane >> 3;                      // row-in-group 0..7
    const int scol = ((lane & 7) ^ sr) * 8;        // swizzled source chunk
    const int rk = w * 16 + sr;                    // source row (+8 for i=1)
    const int ldk = w * 1024 + lane * 8;           // LDS dest element (+512 i=1)

    bf16x8 qa[4];
    {
        const __bf16* qp = q + ((size_t)bh * Tp + qg) * 64 + hi * 8;
#pragma unroll
        for (int s = 0; s < 4; ++s) qa[s] = *(const bf16x8*)(qp + s * 16);
    }

    f32x16 o0 = {}, o1 = {};         // O^T: col=q, row d = (t&3)+8(t>>2)+4hi (+32 for o1)
    float mrow = -3e38f, lrow = 0.f;

    // prologue: stage tiles 0 and 1 (ntmaxB >= 1 always)
#define STG_KV(NT_, BUF_) do { \
    const size_t ko_ = (size_t)(NT_) * 4096, vo_ = (size_t)(NT_) * 64; \
    GLDS(kgb + ko_ + rk * 64 + scol,               &Ks[BUF_][ldk]); \
    GLDS(kgb + ko_ + (rk + 8) * 64 + scol,         &Ks[BUF_][ldk + 512]); \
    GLDS(vgb + vo_ + (size_t)rk * Tp + scol,       &Vs[BUF_][ldk]); \
    GLDS(vgb + vo_ + (size_t)(rk + 8) * Tp + scol, &Vs[BUF_][ldk + 512]); } while (0)

    STG_KV(0, 0);
    STG_KV(1, 1);

#pragma unroll 1
    for (int nt = 0; nt <= ntmaxB; ++nt) {
        const int cur = nt & 1;
        // tile nt ready; leave tile nt+1's 4 loads in flight (never drain mid-loop)
        if (nt < ntmaxB) { asm volatile("s_waitcnt vmcnt(4)" ::: "memory"); }
        else             { asm volatile("s_waitcnt vmcnt(0)" ::: "memory"); }
        __builtin_amdgcn_s_barrier();
        asm volatile("" ::: "memory");

        if (active && nt <= myNt) {
            const int kv0 = nt * 64;

            // S^T = K * Q^T : two 32-kv blocks, K=64 in 4 slices of 16
            f32x16 s0 = {}, s1 = {};
            __builtin_amdgcn_s_setprio(1);
#pragma unroll
            for (int sl = 0; sl < 4; ++sl) {
                const int ch = ((sl * 2 + hi) ^ l7) * 8;
                bf16x8 k0 = *(const bf16x8*)&Ks[cur][l31 * 64 + ch];
                bf16x8 k1 = *(const bf16x8*)&Ks[cur][(32 + l31) * 64 + ch];
                s0 = __builtin_amdgcn_mfma_f32_32x32x16_bf16(k0, qa[sl], s0, 0, 0, 0);
                s1 = __builtin_amdgcn_mfma_f32_32x32x16_bf16(k1, qa[sl], s1, 0, 0, 0);
            }
            __builtin_amdgcn_s_setprio(0);

            if (nt >= qts) {   // mask only on/past the diagonal (wave-uniform)
#pragma unroll
                for (int t = 0; t < 16; ++t) {
                    const int kvg = kv0 + (t & 3) + 8 * (t >> 2) + 4 * hi;
                    const bool v0 = (kvg <= qg) || (qg == 0 && kvg < T_REAL);
                    const bool v1 = (kvg + 32 <= qg) || (qg == 0 && kvg + 32 < T_REAL);
                    s0[t] = v0 ? s0[t] : -1e30f;
                    s1[t] = v1 ? s1[t] : -1e30f;
                }
            }

            // online softmax (exp2 domain); lane pair (l, l+32) shares one q-row
            // pairwise-tree max: depth ~5 instead of a 31-deep serial chain
            float tm[8];
#pragma unroll
            for (int t = 0; t < 8; ++t)
                tm[t] = fmaxf(fmaxf(s0[t], s1[t]), fmaxf(s0[t + 8], s1[t + 8]));
#pragma unroll
            for (int st = 4; st > 0; st >>= 1)
#pragma unroll
                for (int t = 0; t < st; ++t) tm[t] = fmaxf(tm[t], tm[t + st]);
            float mx = fmaxf(tm[0], __shfl_xor(tm[0], 32));
            if (!__all(mx - mrow <= 8.0f)) {      // T13 defer-max
                const float mn = fmaxf(mrow, mx);
                const float alpha = __builtin_amdgcn_exp2f(mrow - mn);
                mrow = mn;
                lrow *= alpha;
#pragma unroll
                for (int t = 0; t < 16; ++t) { o0[t] *= alpha; o1[t] *= alpha; }
            }

            float tr[8];
#pragma unroll
            for (int t = 0; t < 8; ++t) {
                s0[t]     = __builtin_amdgcn_exp2f(s0[t] - mrow);
                s1[t]     = __builtin_amdgcn_exp2f(s1[t] - mrow);
                s0[t + 8] = __builtin_amdgcn_exp2f(s0[t + 8] - mrow);
                s1[t + 8] = __builtin_amdgcn_exp2f(s1[t + 8] - mrow);
                tr[t] = (s0[t] + s1[t]) + (s0[t + 8] + s1[t + 8]);
            }
#pragma unroll
            for (int st = 4; st > 0; st >>= 1)
#pragma unroll
                for (int t = 0; t < st; ++t) tr[t] += tr[t + st];
            lrow += tr[0] + __shfl_xor(tr[0], 32);

            // P B-frags in registers (T12) + PV
            __builtin_amdgcn_s_setprio(1);
#pragma unroll
            for (int m = 0; m < 4; ++m) {
                const f32x16 sb = (m & 2) ? s1 : s0;
                constexpr int SB8[4] = {0, 8, 0, 8};
                const int s8 = SB8[m];
                unsigned a01, a23, a45, a67;
                asm("v_cvt_pk_bf16_f32 %0, %1, %2" : "=v"(a01) : "v"(sb[s8 + 0]), "v"(sb[s8 + 1]));
                asm("v_cvt_pk_bf16_f32 %0, %1, %2" : "=v"(a23) : "v"(sb[s8 + 2]), "v"(sb[s8 + 3]));
                asm("v_cvt_pk_bf16_f32 %0, %1, %2" : "=v"(a45) : "v"(sb[s8 + 4]), "v"(sb[s8 + 5]));
                asm("v_cvt_pk_bf16_f32 %0, %1, %2" : "=v"(a67) : "v"(sb[s8 + 6]), "v"(sb[s8 + 7]));
                asm("v_permlane32_swap_b32 %0, %1" : "+v"(a01), "+v"(a45));
                asm("v_permlane32_swap_b32 %0, %1" : "+v"(a23), "+v"(a67));
                union { unsigned u[4]; bf16x8 v; } pf;
                pf.u[0] = a01; pf.u[1] = a23; pf.u[2] = a45; pf.u[3] = a67;
                const int ch = ((m * 2 + hi) ^ l7) * 8;
                bf16x8 v0 = *(const bf16x8*)&Vs[cur][l31 * 64 + ch];
                bf16x8 v1 = *(const bf16x8*)&Vs[cur][(32 + l31) * 64 + ch];
                o0 = __builtin_amdgcn_mfma_f32_32x32x16_bf16(v0, pf.v, o0, 0, 0, 0);
                o1 = __builtin_amdgcn_mfma_f32_32x32x16_bf16(v1, pf.v, o1, 0, 0, 0);
            }
            __builtin_amdgcn_s_setprio(0);
        }

        // all waves done reading buf[cur]; then refill it with tile nt+2
        asm volatile("" ::: "memory");
        __builtin_amdgcn_s_barrier();
        asm volatile("" ::: "memory");
        if (nt + 2 <= ntmaxB) STG_KV(nt + 2, cur);
    }
#undef STG_KV

    // y[b, t=qg, h*64 + d], d = g*8 + hi*4 + j (+32 for o1); packed 8B stores
    if (active && qg < T_REAL) {
        const float inv = 1.0f / lrow;
        __bf16* yp = y + ((size_t)(b * T_REAL + qg)) * 1024 + h * 64 + hi * 4;
#pragma unroll
        for (int g = 0; g < 4; ++g) {
            bf16x4 w0, w1;
            w0.x = (__bf16)(o0[g * 4 + 0] * inv);
            w0.y = (__bf16)(o0[g * 4 + 1] * inv);
            w0.z = (__bf16)(o0[g * 4 + 2] * inv);
            w0.w = (__bf16)(o0[g * 4 + 3] * inv);
            w1.x = (__bf16)(o1[g * 4 + 0] * inv);
            w1.y = (__bf16)(o1[g * 4 + 1] * inv);
            w1.z = (__bf16)(o1[g * 4 + 2] * inv);
            w1.w = (__bf16)(o1[g * 4 + 3] * inv);
            *(bf16x4*)(yp + g * 8)      = w0;
            *(bf16x4*)(yp + 32 + g * 8) = w1;
        }
    }
}

// ---------------- launch ----------------
extern "C" void kernel_launch(void* const* d_in, const int* in_sizes, int n_in,
                              void* d_out, int out_size, void* d_ws, size_t ws_size,
                              hipStream_t stream) {
    const float* x  = (const float*)d_in[0];
    const float* Wa = (const float*)d_in[1];
    const float* Wp = (const float*)d_in[2];
    float* out = (float*)d_out;

    char* ws = (char*)d_ws;
    constexpr size_t SZ_XB  = (size_t)Mp * GK * 2;
    constexpr size_t SZ_WAT = (size_t)3072 * GK * 2;
    constexpr size_t SZ_WPT = (size_t)1024 * GK * 2;
    constexpr size_t SZ_QK  = (size_t)64 * Tp * 64 * 2;
    __bf16* xb   = (__bf16*)(ws);
    __bf16* WaT  = (__bf16*)(ws + SZ_XB);
    __bf16* WpT  = (__bf16*)(ws + SZ_XB + SZ_WAT);
    __bf16* qb   = (__bf16*)(ws + SZ_XB + SZ_WAT + SZ_WPT);
    __bf16* kb   = (__bf16*)(ws + SZ_XB + SZ_WAT + SZ_WPT + SZ_QK);
    __bf16* vTb  = (__bf16*)(ws + SZ_XB + SZ_WAT + SZ_WPT + 2 * SZ_QK);
    __bf16* shrd = (__bf16*)(ws + SZ_XB + SZ_WAT + SZ_WPT + 3 * SZ_QK);
    __bf16* vpre = shrd;   // v [bh][t][d], consumed by transpose_v before attn
    __bf16* yb   = shrd;   // attn output, written after vpre is dead

    prep<<<9472, 256, 0, stream>>>(x, xb, Wa, WaT, Wp, WpT);
    gemm256<<<dim3(12, 33), 512, 0, stream>>>(xb, WaT, qb, kb, vpre);
    transpose_v<<<dim3(33, 64), 256, 0, stream>>>(vpre, vTb);
    attn<<<1088, 256, 0, stream>>>(qb, kb, vTb, yb);
    gemm128<1><<<dim3(8, 65), 256, 0, stream>>>(yb, WpT, out, nullptr, nullptr, nullptr);
}